// Round 2
// baseline (535.643 us; speedup 1.0000x reference)
//
#include <hip/hip_runtime.h>
#include <cstdint>

#define TSIZE (1u << 19)
#define MASKU (TSIZE - 1u)
#define P1U 2654435761u

// One thread per point; 16 levels fully unrolled.
// Levels 0-11: direct index (c0*res + c1). Levels 12-15: hash (c0 ^ c1*P1) & MASK
// (searchsorted in the reference is an identity lookup -- see analysis).
__global__ __launch_bounds__(256) void hashenc_kernel(
    const float2* __restrict__ xs,
    const float* __restrict__ tables,
    float* __restrict__ out, int B) {
  int p = blockIdx.x * 256 + threadIdx.x;
  if (p >= B) return;
  float2 xv = xs[p];

  float feat[32];
  // RES[15]: float32-ambiguous (2047 vs 2048) -- hypothesis B = 2047.
  constexpr int RESV[16] = {16, 22, 30, 42, 58, 80, 111, 153,
                            212, 294, 406, 561, 776, 1072, 1482, 2047};

#pragma unroll
  for (int l = 0; l < 16; ++l) {
    const int res = RESV[l];
    // reference: gs = float32(python_double(2048.0 / res))
    const float gs = (float)(2048.0 / (double)res);
    float f0 = floorf(xv.x / gs);
    float f1 = floorf(xv.y / gs);
    float g0 = f0 * gs;
    float g1 = f1 * gs;
    // replicate (x - gmin) / (gmax - gmin) exactly (no simplification to /gs)
    float w0 = (xv.x - g0) / ((g0 + gs) - g0);
    float w1 = (xv.y - g1) / ((g1 + gs) - g1);
    int b0 = (int)f0;
    int b1 = (int)f1;

    const float2* tab = reinterpret_cast<const float2*>(tables) + (size_t)l * TSIZE;
    float2 e00, e01, e10, e11;
    if ((res + 1) * (res + 1) <= (int)TSIZE) {
      int base = b0 * res + b1;
      e00 = tab[base];
      e01 = tab[base + 1];
      e10 = tab[base + res];
      e11 = tab[base + res + 1];
    } else {
      uint32_t u0 = (uint32_t)b0;
      uint32_t u1m = (uint32_t)b1 * P1U;
      e00 = tab[(u0 ^ u1m) & MASKU];
      e01 = tab[(u0 ^ (u1m + P1U)) & MASKU];
      e10 = tab[((u0 + 1u) ^ u1m) & MASKU];
      e11 = tab[((u0 + 1u) ^ (u1m + P1U)) & MASKU];
    }

    float omw0 = 1.0f - w0;
    float omw1 = 1.0f - w1;
    float c0x = e00.x * omw1 + e01.x * w1;
    float c0y = e00.y * omw1 + e01.y * w1;
    float c1x = e10.x * omw1 + e11.x * w1;
    float c1y = e10.y * omw1 + e11.y * w1;
    feat[2 * l]     = c0x * omw0 + c1x * w0;
    feat[2 * l + 1] = c0y * omw0 + c1y * w0;
  }

  float4* o = reinterpret_cast<float4*>(out) + (size_t)p * 8;
#pragma unroll
  for (int j = 0; j < 8; ++j) {
    o[j] = make_float4(feat[4 * j], feat[4 * j + 1], feat[4 * j + 2], feat[4 * j + 3]);
  }
}

extern "C" void kernel_launch(void* const* d_in, const int* in_sizes, int n_in,
                              void* d_out, int out_size, void* d_ws, size_t ws_size,
                              hipStream_t stream) {
  const float2* xs = (const float2*)d_in[0];
  const float* tables = (const float*)d_in[1];
  float* out = (float*)d_out;
  int B = in_sizes[0] / 2;
  int blocks = (B + 255) / 256;
  hipLaunchKernelGGL(hashenc_kernel, dim3(blocks), dim3(256), 0, stream,
                     xs, tables, out, B);
}

// Round 3
// 534.645 us; speedup vs baseline: 1.0019x; 1.0019x over previous
//
#include <hip/hip_runtime.h>
#include <cstdint>

#define TSIZE (1u << 19)
#define MASKU (TSIZE - 1u)
#define P1U 2654435761u

// One thread per point; 16 levels fully unrolled.
// Levels 0-11: direct index (c0*res + c1) -> corner pairs (e00,e01) and
// (e10,e11) are ADJACENT 8B table entries, so each pair is one 16B gather
// (dwordx4 at 8B alignment -- CDNA global loads need only dword alignment).
// Levels 12-15: hash (c0 ^ c1*P1) & MASK; searchsorted in the reference is
// an identity lookup (all queried vertex hashes are present in SORTED).
__global__ __launch_bounds__(256) void hashenc_kernel(
    const float2* __restrict__ xs,
    const float* __restrict__ tables,
    float* __restrict__ out, int B) {
  int p = blockIdx.x * 256 + threadIdx.x;
  if (p >= B) return;
  float2 xv = xs[p];

  float feat[32];
  // RES[15] = 2047 (verified round 2: numpy f32 exp/log chain floors to 2047).
  constexpr int RESV[16] = {16, 22, 30, 42, 58, 80, 111, 153,
                            212, 294, 406, 561, 776, 1072, 1482, 2047};

#pragma unroll
  for (int l = 0; l < 16; ++l) {
    const int res = RESV[l];
    // reference: gs = float32(python_double(2048.0 / res))
    const float gs = (float)(2048.0 / (double)res);
    float f0 = floorf(xv.x / gs);
    float f1 = floorf(xv.y / gs);
    float g0 = f0 * gs;
    float g1 = f1 * gs;
    // replicate (x - gmin) / (gmax - gmin) exactly (no simplification to /gs)
    float w0 = (xv.x - g0) / ((g0 + gs) - g0);
    float w1 = (xv.y - g1) / ((g1 + gs) - g1);
    int b0 = (int)f0;
    int b1 = (int)f1;

    const float2* tab = reinterpret_cast<const float2*>(tables) + (size_t)l * TSIZE;
    float2 e00, e01, e10, e11;
    if ((res + 1) * (res + 1) <= (int)TSIZE) {
      int base = b0 * res + b1;
      // fused pair gathers: identical bytes as 4x float2, half the gather instrs
      float4 lo = *reinterpret_cast<const float4*>(tab + base);
      float4 hi = *reinterpret_cast<const float4*>(tab + base + res);
      e00 = make_float2(lo.x, lo.y);
      e01 = make_float2(lo.z, lo.w);
      e10 = make_float2(hi.x, hi.y);
      e11 = make_float2(hi.z, hi.w);
    } else {
      uint32_t u0 = (uint32_t)b0;
      uint32_t u1m = (uint32_t)b1 * P1U;
      e00 = tab[(u0 ^ u1m) & MASKU];
      e01 = tab[(u0 ^ (u1m + P1U)) & MASKU];
      e10 = tab[((u0 + 1u) ^ u1m) & MASKU];
      e11 = tab[((u0 + 1u) ^ (u1m + P1U)) & MASKU];
    }

    float omw0 = 1.0f - w0;
    float omw1 = 1.0f - w1;
    float c0x = e00.x * omw1 + e01.x * w1;
    float c0y = e00.y * omw1 + e01.y * w1;
    float c1x = e10.x * omw1 + e11.x * w1;
    float c1y = e10.y * omw1 + e11.y * w1;
    feat[2 * l]     = c0x * omw0 + c1x * w0;
    feat[2 * l + 1] = c0y * omw0 + c1y * w0;
  }

  float4* o = reinterpret_cast<float4*>(out) + (size_t)p * 8;
#pragma unroll
  for (int j = 0; j < 8; ++j) {
    o[j] = make_float4(feat[4 * j], feat[4 * j + 1], feat[4 * j + 2], feat[4 * j + 3]);
  }
}

extern "C" void kernel_launch(void* const* d_in, const int* in_sizes, int n_in,
                              void* d_out, int out_size, void* d_ws, size_t ws_size,
                              hipStream_t stream) {
  const float2* xs = (const float2*)d_in[0];
  const float* tables = (const float*)d_in[1];
  float* out = (float*)d_out;
  int B = in_sizes[0] / 2;
  int blocks = (B + 255) / 256;
  hipLaunchKernelGGL(hashenc_kernel, dim3(blocks), dim3(256), 0, stream,
                     xs, tables, out, B);
}

// Round 4
// 439.681 us; speedup vs baseline: 1.2183x; 1.2160x over previous
//
#include <hip/hip_runtime.h>
#include <cstdint>

#define TSIZE (1u << 19)
#define MASKU (TSIZE - 1u)
#define P1U 2654435761u
#define BINS_X 128
#define NBINS (BINS_X * BINS_X)

// ---------------- sort machinery: counting sort into 16x16-px bins ----------

__global__ __launch_bounds__(256) void zero_kernel(int* __restrict__ p, int n) {
  int i = blockIdx.x * 256 + threadIdx.x;
  if (i < n) p[i] = 0;
}

__device__ __forceinline__ int bin_of(float2 xv) {
  int bx = min((int)(xv.x * 0.0625f), BINS_X - 1);
  int by = min((int)(xv.y * 0.0625f), BINS_X - 1);
  return bx * BINS_X + by;
}

__global__ __launch_bounds__(256) void hist_kernel(const float2* __restrict__ xs,
                                                   int* __restrict__ hist, int B) {
  int p = blockIdx.x * 256 + threadIdx.x;
  if (p >= B) return;
  atomicAdd(&hist[bin_of(xs[p])], 1);
}

// one block, 1024 threads, 16 bins/thread
__global__ __launch_bounds__(1024) void scan_kernel(const int* __restrict__ hist,
                                                    int* __restrict__ base) {
  __shared__ int part[1024];
  int tid = threadIdx.x;
  int loc[16];
  int s = 0;
#pragma unroll
  for (int j = 0; j < 16; ++j) { loc[j] = hist[tid * 16 + j]; s += loc[j]; }
  part[tid] = s;
  __syncthreads();
  for (int off = 1; off < 1024; off <<= 1) {
    int v = (tid >= off) ? part[tid - off] : 0;
    __syncthreads();
    part[tid] += v;
    __syncthreads();
  }
  int run = (tid == 0) ? 0 : part[tid - 1];
#pragma unroll
  for (int j = 0; j < 16; ++j) { base[tid * 16 + j] = run; run += loc[j]; }
}

__global__ __launch_bounds__(256) void scatter_kernel(
    const float2* __restrict__ xs, const int* __restrict__ base,
    int* __restrict__ cursor, float2* __restrict__ sx, int* __restrict__ sidx, int B) {
  int p = blockIdx.x * 256 + threadIdx.x;
  if (p >= B) return;
  float2 xv = xs[p];
  int bin = bin_of(xv);
  int pos = base[bin] + atomicAdd(&cursor[bin], 1);
  sx[pos] = xv;
  sidx[pos] = p;
}

// ---------------- main embed kernel (numerics frozen from round 2) ----------

// RES[15] = 2047 (verified round 2). Levels 0-11 direct, 12-15 hash;
// searchsorted in the reference is an identity lookup.
template <bool SORTED>
__global__ __launch_bounds__(256) void hashenc_kernel(
    const float2* __restrict__ xs, const int* __restrict__ sidx,
    const float* __restrict__ tables, float* __restrict__ out, int B) {
  int bid = blockIdx.x;
  if (SORTED) {
    // XCD chunk swizzle: contiguous 1/8 of the (spatially sorted) blocks per XCD
    int nb = gridDim.x;           // 8192, divisible by 8
    int chunk = nb >> 3;
    bid = (bid & 7) * chunk + (bid >> 3);
  }
  int p = bid * 256 + threadIdx.x;
  if (p >= B) return;
  float2 xv = xs[p];
  int orig = SORTED ? sidx[p] : p;

  float feat[32];
  constexpr int RESV[16] = {16, 22, 30, 42, 58, 80, 111, 153,
                            212, 294, 406, 561, 776, 1072, 1482, 2047};

#pragma unroll
  for (int l = 0; l < 16; ++l) {
    const int res = RESV[l];
    const float gs = (float)(2048.0 / (double)res);  // f32(double(2048/res))
    float f0 = floorf(xv.x / gs);
    float f1 = floorf(xv.y / gs);
    float g0 = f0 * gs;
    float g1 = f1 * gs;
    float w0 = (xv.x - g0) / ((g0 + gs) - g0);
    float w1 = (xv.y - g1) / ((g1 + gs) - g1);
    int b0 = (int)f0;
    int b1 = (int)f1;

    const float2* tab = reinterpret_cast<const float2*>(tables) + (size_t)l * TSIZE;
    float2 e00, e01, e10, e11;
    if ((res + 1) * (res + 1) <= (int)TSIZE) {
      int base = b0 * res + b1;
      float4 lo = *reinterpret_cast<const float4*>(tab + base);
      float4 hi = *reinterpret_cast<const float4*>(tab + base + res);
      e00 = make_float2(lo.x, lo.y);
      e01 = make_float2(lo.z, lo.w);
      e10 = make_float2(hi.x, hi.y);
      e11 = make_float2(hi.z, hi.w);
    } else {
      uint32_t u0 = (uint32_t)b0;
      uint32_t u1m = (uint32_t)b1 * P1U;
      e00 = tab[(u0 ^ u1m) & MASKU];
      e01 = tab[(u0 ^ (u1m + P1U)) & MASKU];
      e10 = tab[((u0 + 1u) ^ u1m) & MASKU];
      e11 = tab[((u0 + 1u) ^ (u1m + P1U)) & MASKU];
    }

    float omw0 = 1.0f - w0;
    float omw1 = 1.0f - w1;
    float c0x = e00.x * omw1 + e01.x * w1;
    float c0y = e00.y * omw1 + e01.y * w1;
    float c1x = e10.x * omw1 + e11.x * w1;
    float c1y = e10.y * omw1 + e11.y * w1;
    feat[2 * l]     = c0x * omw0 + c1x * w0;
    feat[2 * l + 1] = c0y * omw0 + c1y * w0;
  }

  float4* o = reinterpret_cast<float4*>(out) + (size_t)orig * 8;
#pragma unroll
  for (int j = 0; j < 8; ++j) {
    o[j] = make_float4(feat[4 * j], feat[4 * j + 1], feat[4 * j + 2], feat[4 * j + 3]);
  }
}

extern "C" void kernel_launch(void* const* d_in, const int* in_sizes, int n_in,
                              void* d_out, int out_size, void* d_ws, size_t ws_size,
                              hipStream_t stream) {
  const float2* xs = (const float2*)d_in[0];
  const float* tables = (const float*)d_in[1];
  float* out = (float*)d_out;
  int B = in_sizes[0] / 2;
  int blocks = (B + 255) / 256;

  // ws layout: sx (8B*B) | sidx (4B*B) | hist | cursor | base
  size_t off_sx = 0;
  size_t off_sidx = off_sx + (size_t)B * 8;
  size_t off_hist = off_sidx + (size_t)B * 4;
  size_t off_cursor = off_hist + (size_t)NBINS * 4;
  size_t off_base = off_cursor + (size_t)NBINS * 4;
  size_t need = off_base + (size_t)NBINS * 4;

  if (ws_size >= need && (blocks & 7) == 0) {
    char* ws = (char*)d_ws;
    float2* sx = (float2*)(ws + off_sx);
    int* sidx = (int*)(ws + off_sidx);
    int* hist = (int*)(ws + off_hist);
    int* cursor = (int*)(ws + off_cursor);  // contiguous after hist
    int* base = (int*)(ws + off_base);

    int zn = 2 * NBINS;  // hist + cursor contiguous
    hipLaunchKernelGGL(zero_kernel, dim3((zn + 255) / 256), dim3(256), 0, stream, hist, zn);
    hipLaunchKernelGGL(hist_kernel, dim3(blocks), dim3(256), 0, stream, xs, hist, B);
    hipLaunchKernelGGL(scan_kernel, dim3(1), dim3(1024), 0, stream, hist, base);
    hipLaunchKernelGGL(scatter_kernel, dim3(blocks), dim3(256), 0, stream,
                       xs, base, cursor, sx, sidx, B);
    hipLaunchKernelGGL((hashenc_kernel<true>), dim3(blocks), dim3(256), 0, stream,
                       sx, sidx, tables, out, B);
  } else {
    hipLaunchKernelGGL((hashenc_kernel<false>), dim3(blocks), dim3(256), 0, stream,
                       xs, (const int*)nullptr, tables, out, B);
  }
}

// Round 5
// 381.226 us; speedup vs baseline: 1.4051x; 1.1533x over previous
//
#include <hip/hip_runtime.h>
#include <cstdint>

#define TSIZE (1u << 19)
#define MASKU (TSIZE - 1u)
#define P1U 2654435761u
#define BINS_X 128
#define NBINS (BINS_X * BINS_X)

// ---------------- sort machinery: counting sort into 16x16-px bins ----------

__device__ __forceinline__ int bin_of(float2 xv) {
  int bx = min((int)(xv.x * 0.0625f), BINS_X - 1);
  int by = min((int)(xv.y * 0.0625f), BINS_X - 1);
  return bx * BINS_X + by;
}

__global__ __launch_bounds__(256) void hist_kernel(const float2* __restrict__ xs,
                                                   int* __restrict__ hist, int B) {
  int p = blockIdx.x * 256 + threadIdx.x;
  if (p >= B) return;
  atomicAdd(&hist[bin_of(xs[p])], 1);
}

// one block, 1024 threads, 16 bins/thread; writes exclusive-prefix into base
__global__ __launch_bounds__(1024) void scan_kernel(const int* __restrict__ hist,
                                                    int* __restrict__ base) {
  __shared__ int part[1024];
  int tid = threadIdx.x;
  int loc[16];
  int s = 0;
#pragma unroll
  for (int j = 0; j < 16; ++j) { loc[j] = hist[tid * 16 + j]; s += loc[j]; }
  part[tid] = s;
  __syncthreads();
  for (int off = 1; off < 1024; off <<= 1) {
    int v = (tid >= off) ? part[tid - off] : 0;
    __syncthreads();
    part[tid] += v;
    __syncthreads();
  }
  int run = (tid == 0) ? 0 : part[tid - 1];
#pragma unroll
  for (int j = 0; j < 16; ++j) { base[tid * 16 + j] = run; run += loc[j]; }
}

// scatter variants: atomicAdd directly on base (base is consumed -> no cursor)
__global__ __launch_bounds__(256) void scatter_packed(
    const float2* __restrict__ xs, int* __restrict__ base,
    float4* __restrict__ recs, int B) {
  int p = blockIdx.x * 256 + threadIdx.x;
  if (p >= B) return;
  float2 xv = xs[p];
  int pos = atomicAdd(&base[bin_of(xv)], 1);
  recs[pos] = make_float4(xv.x, xv.y, __int_as_float(p), 0.0f);
}

__global__ __launch_bounds__(256) void scatter_split(
    const float2* __restrict__ xs, int* __restrict__ base,
    float2* __restrict__ sx, int* __restrict__ sidx, int B) {
  int p = blockIdx.x * 256 + threadIdx.x;
  if (p >= B) return;
  float2 xv = xs[p];
  int pos = atomicAdd(&base[bin_of(xv)], 1);
  sx[pos] = xv;
  sidx[pos] = p;
}

// ---------------- main embed kernel (numerics frozen from round 2) ----------
// MLP restructure: phase 1 issues ALL 40 gathers (16 levels) into register
// arrays; phase 2 lerps from registers. Identical FP ops, reordered only.
// RES[15] = 2047 (verified round 2). searchsorted == identity lookup.
// MODE: 0 = unsorted fallback, 1 = split (sx+sidx), 2 = packed 16B records.
template <int MODE>
__global__ __launch_bounds__(256, 2) void hashenc_kernel(
    const float2* __restrict__ xs, const int* __restrict__ sidx,
    const float4* __restrict__ recs,
    const float* __restrict__ tables, float* __restrict__ out, int B) {
  int bid = blockIdx.x;
  if (MODE != 0) {
    int nb = gridDim.x;  // divisible by 8 (guarded at launch)
    int chunk = nb >> 3;
    bid = (bid & 7) * chunk + (bid >> 3);
  }
  int p = bid * 256 + threadIdx.x;
  if (p >= B) return;
  float2 xv;
  int orig;
  if (MODE == 2) {
    float4 r = recs[p];
    xv = make_float2(r.x, r.y);
    orig = __float_as_int(r.z);
  } else if (MODE == 1) {
    xv = xs[p];
    orig = sidx[p];
  } else {
    xv = xs[p];
    orig = p;
  }

  constexpr int RESV[16] = {16, 22, 30, 42, 58, 80, 111, 153,
                            212, 294, 406, 561, 776, 1072, 1482, 2047};
  const float2* tabs = reinterpret_cast<const float2*>(tables);

  float4 lo[12], hi[12];
  float2 eh[4][4];
  float w0a[16], w1a[16];

  // phase 1a: direct levels 0-11 -- two fused 16B pair-gathers each
#pragma unroll
  for (int l = 0; l < 12; ++l) {
    const int res = RESV[l];
    const float gs = (float)(2048.0 / (double)res);  // f32(double(2048/res))
    float f0 = floorf(xv.x / gs);
    float f1 = floorf(xv.y / gs);
    float g0 = f0 * gs;
    float g1 = f1 * gs;
    w0a[l] = (xv.x - g0) / ((g0 + gs) - g0);
    w1a[l] = (xv.y - g1) / ((g1 + gs) - g1);
    int base = (int)f0 * res + (int)f1;
    const float2* tab = tabs + (size_t)l * TSIZE;
    lo[l] = *reinterpret_cast<const float4*>(tab + base);
    hi[l] = *reinterpret_cast<const float4*>(tab + base + res);
  }
  // phase 1b: hash levels 12-15 -- four 8B gathers each
#pragma unroll
  for (int l = 0; l < 4; ++l) {
    const int res = RESV[12 + l];
    const float gs = (float)(2048.0 / (double)res);
    float f0 = floorf(xv.x / gs);
    float f1 = floorf(xv.y / gs);
    float g0 = f0 * gs;
    float g1 = f1 * gs;
    w0a[12 + l] = (xv.x - g0) / ((g0 + gs) - g0);
    w1a[12 + l] = (xv.y - g1) / ((g1 + gs) - g1);
    uint32_t u0 = (uint32_t)(int)f0;
    uint32_t u1m = (uint32_t)(int)f1 * P1U;
    const float2* tab = tabs + (size_t)(12 + l) * TSIZE;
    eh[l][0] = tab[(u0 ^ u1m) & MASKU];
    eh[l][1] = tab[(u0 ^ (u1m + P1U)) & MASKU];
    eh[l][2] = tab[((u0 + 1u) ^ u1m) & MASKU];
    eh[l][3] = tab[((u0 + 1u) ^ (u1m + P1U)) & MASKU];
  }

  // phase 2: lerp from registers
  float feat[32];
#pragma unroll
  for (int l = 0; l < 12; ++l) {
    float w0 = w0a[l], w1 = w1a[l];
    float omw0 = 1.0f - w0, omw1 = 1.0f - w1;
    float c0x = lo[l].x * omw1 + lo[l].z * w1;
    float c0y = lo[l].y * omw1 + lo[l].w * w1;
    float c1x = hi[l].x * omw1 + hi[l].z * w1;
    float c1y = hi[l].y * omw1 + hi[l].w * w1;
    feat[2 * l]     = c0x * omw0 + c1x * w0;
    feat[2 * l + 1] = c0y * omw0 + c1y * w0;
  }
#pragma unroll
  for (int l = 0; l < 4; ++l) {
    float w0 = w0a[12 + l], w1 = w1a[12 + l];
    float omw0 = 1.0f - w0, omw1 = 1.0f - w1;
    float c0x = eh[l][0].x * omw1 + eh[l][1].x * w1;
    float c0y = eh[l][0].y * omw1 + eh[l][1].y * w1;
    float c1x = eh[l][2].x * omw1 + eh[l][3].x * w1;
    float c1y = eh[l][2].y * omw1 + eh[l][3].y * w1;
    feat[24 + 2 * l]     = c0x * omw0 + c1x * w0;
    feat[24 + 2 * l + 1] = c0y * omw0 + c1y * w0;
  }

  float4* o = reinterpret_cast<float4*>(out) + (size_t)orig * 8;
#pragma unroll
  for (int j = 0; j < 8; ++j) {
    o[j] = make_float4(feat[4 * j], feat[4 * j + 1], feat[4 * j + 2], feat[4 * j + 3]);
  }
}

extern "C" void kernel_launch(void* const* d_in, const int* in_sizes, int n_in,
                              void* d_out, int out_size, void* d_ws, size_t ws_size,
                              hipStream_t stream) {
  const float2* xs = (const float2*)d_in[0];
  const float* tables = (const float*)d_in[1];
  float* out = (float*)d_out;
  int B = in_sizes[0] / 2;
  int blocks = (B + 255) / 256;
  char* ws = (char*)d_ws;

  // packed layout: recs (16B*B) | hist | base
  size_t p_recs = 0, p_hist = p_recs + (size_t)B * 16, p_base = p_hist + (size_t)NBINS * 4;
  size_t need_packed = p_base + (size_t)NBINS * 4;
  // split layout: sx (8B*B) | sidx (4B*B) | hist | base
  size_t s_sx = 0, s_sidx = s_sx + (size_t)B * 8, s_hist = s_sidx + (size_t)B * 4,
         s_base = s_hist + (size_t)NBINS * 4;
  size_t need_split = s_base + (size_t)NBINS * 4;

  bool grid_ok = (blocks & 7) == 0;
  if (grid_ok && ws_size >= need_packed) {
    float4* recs = (float4*)(ws + p_recs);
    int* hist = (int*)(ws + p_hist);
    int* base = (int*)(ws + p_base);
    hipMemsetAsync(hist, 0, (size_t)NBINS * 4, stream);
    hipLaunchKernelGGL(hist_kernel, dim3(blocks), dim3(256), 0, stream, xs, hist, B);
    hipLaunchKernelGGL(scan_kernel, dim3(1), dim3(1024), 0, stream, hist, base);
    hipLaunchKernelGGL(scatter_packed, dim3(blocks), dim3(256), 0, stream, xs, base, recs, B);
    hipLaunchKernelGGL((hashenc_kernel<2>), dim3(blocks), dim3(256), 0, stream,
                       nullptr, nullptr, recs, tables, out, B);
  } else if (grid_ok && ws_size >= need_split) {
    float2* sx = (float2*)(ws + s_sx);
    int* sidx = (int*)(ws + s_sidx);
    int* hist = (int*)(ws + s_hist);
    int* base = (int*)(ws + s_base);
    hipMemsetAsync(hist, 0, (size_t)NBINS * 4, stream);
    hipLaunchKernelGGL(hist_kernel, dim3(blocks), dim3(256), 0, stream, xs, hist, B);
    hipLaunchKernelGGL(scan_kernel, dim3(1), dim3(1024), 0, stream, hist, base);
    hipLaunchKernelGGL(scatter_split, dim3(blocks), dim3(256), 0, stream, xs, base, sx, sidx, B);
    hipLaunchKernelGGL((hashenc_kernel<1>), dim3(blocks), dim3(256), 0, stream,
                       sx, sidx, nullptr, tables, out, B);
  } else {
    hipLaunchKernelGGL((hashenc_kernel<0>), dim3(blocks), dim3(256), 0, stream,
                       xs, nullptr, nullptr, tables, out, B);
  }
}

// Round 6
// 320.924 us; speedup vs baseline: 1.6691x; 1.1879x over previous
//
#include <hip/hip_runtime.h>
#include <cstdint>

#define TSIZE (1u << 19)
#define MASKU (TSIZE - 1u)
#define P1U 2654435761u

// fallback (round-5) sort params
#define BINS_X 128
#define NBINS (BINS_X * BINS_X)
// capacity-bin params (round-6 path)
#define CBINS_X 64
#define NCB (CBINS_X * CBINS_X)     // 4096 bins of 32x32 px
#define CAP 576                     // mean 512 + 2.8 sigma; 9 waves per bin
#define SLOTS (NCB * CAP)           // 2,359,296 -> 9216 blocks of 256

// ---------------- embed core (numerics FROZEN since round 2) ----------------
// RES[15] = 2047 (verified round 2). Levels 0-11 direct (fused 16B pair
// gathers); 12-15 hash; reference searchsorted == identity lookup.
// MLP structure: all 40 gathers issued before any lerp.
__device__ __forceinline__ void embed_point(float2 xv, int orig,
                                            const float* __restrict__ tables,
                                            float* __restrict__ out) {
  constexpr int RESV[16] = {16, 22, 30, 42, 58, 80, 111, 153,
                            212, 294, 406, 561, 776, 1072, 1482, 2047};
  const float2* tabs = reinterpret_cast<const float2*>(tables);

  float4 lo[12], hi[12];
  float2 eh[4][4];
  float w0a[16], w1a[16];

#pragma unroll
  for (int l = 0; l < 12; ++l) {
    const int res = RESV[l];
    const float gs = (float)(2048.0 / (double)res);  // f32(double(2048/res))
    float f0 = floorf(xv.x / gs);
    float f1 = floorf(xv.y / gs);
    float g0 = f0 * gs;
    float g1 = f1 * gs;
    w0a[l] = (xv.x - g0) / ((g0 + gs) - g0);
    w1a[l] = (xv.y - g1) / ((g1 + gs) - g1);
    int base = (int)f0 * res + (int)f1;
    const float2* tab = tabs + (size_t)l * TSIZE;
    lo[l] = *reinterpret_cast<const float4*>(tab + base);
    hi[l] = *reinterpret_cast<const float4*>(tab + base + res);
  }
#pragma unroll
  for (int l = 0; l < 4; ++l) {
    const int res = RESV[12 + l];
    const float gs = (float)(2048.0 / (double)res);
    float f0 = floorf(xv.x / gs);
    float f1 = floorf(xv.y / gs);
    float g0 = f0 * gs;
    float g1 = f1 * gs;
    w0a[12 + l] = (xv.x - g0) / ((g0 + gs) - g0);
    w1a[12 + l] = (xv.y - g1) / ((g1 + gs) - g1);
    uint32_t u0 = (uint32_t)(int)f0;
    uint32_t u1m = (uint32_t)(int)f1 * P1U;
    const float2* tab = tabs + (size_t)(12 + l) * TSIZE;
    eh[l][0] = tab[(u0 ^ u1m) & MASKU];
    eh[l][1] = tab[(u0 ^ (u1m + P1U)) & MASKU];
    eh[l][2] = tab[((u0 + 1u) ^ u1m) & MASKU];
    eh[l][3] = tab[((u0 + 1u) ^ (u1m + P1U)) & MASKU];
  }

  float feat[32];
#pragma unroll
  for (int l = 0; l < 12; ++l) {
    float w0 = w0a[l], w1 = w1a[l];
    float omw0 = 1.0f - w0, omw1 = 1.0f - w1;
    float c0x = lo[l].x * omw1 + lo[l].z * w1;
    float c0y = lo[l].y * omw1 + lo[l].w * w1;
    float c1x = hi[l].x * omw1 + hi[l].z * w1;
    float c1y = hi[l].y * omw1 + hi[l].w * w1;
    feat[2 * l]     = c0x * omw0 + c1x * w0;
    feat[2 * l + 1] = c0y * omw0 + c1y * w0;
  }
#pragma unroll
  for (int l = 0; l < 4; ++l) {
    float w0 = w0a[12 + l], w1 = w1a[12 + l];
    float omw0 = 1.0f - w0, omw1 = 1.0f - w1;
    float c0x = eh[l][0].x * omw1 + eh[l][1].x * w1;
    float c0y = eh[l][0].y * omw1 + eh[l][1].y * w1;
    float c1x = eh[l][2].x * omw1 + eh[l][3].x * w1;
    float c1y = eh[l][2].y * omw1 + eh[l][3].y * w1;
    feat[24 + 2 * l]     = c0x * omw0 + c1x * w0;
    feat[24 + 2 * l + 1] = c0y * omw0 + c1y * w0;
  }

  float4* o = reinterpret_cast<float4*>(out) + (size_t)orig * 8;
#pragma unroll
  for (int j = 0; j < 8; ++j) {
    o[j] = make_float4(feat[4 * j], feat[4 * j + 1], feat[4 * j + 2], feat[4 * j + 3]);
  }
}

// ---------------- round-6 path: capacity bins (no hist, no scan) -----------

__device__ __forceinline__ int bin_cap(float2 xv) {
  int bx = min((int)(xv.x * 0.03125f), CBINS_X - 1);
  int by = min((int)(xv.y * 0.03125f), CBINS_X - 1);
  return bx * CBINS_X + by;
}

__global__ __launch_bounds__(256) void scatter_cap(
    const float2* __restrict__ xs, int* __restrict__ cnt,
    float4* __restrict__ recs, int* __restrict__ ovf, int* __restrict__ ovf_cnt,
    int B) {
  int p = blockIdx.x * 256 + threadIdx.x;
  if (p >= B) return;
  float2 xv = xs[p];
  int bin = bin_cap(xv);
  int pos = atomicAdd(&cnt[bin], 1);
  if (pos < CAP) {
    recs[(size_t)bin * CAP + pos] = make_float4(xv.x, xv.y, __int_as_float(p), 0.0f);
  } else {
    int o = atomicAdd(ovf_cnt, 1);
    ovf[o] = p;  // ovf capacity == B: can never overflow
  }
}

__global__ __launch_bounds__(256, 2) void hashenc_cap(
    const float4* __restrict__ recs, const int* __restrict__ cnt,
    const float* __restrict__ tables, float* __restrict__ out) {
  int bid = blockIdx.x;
  int nb = gridDim.x;  // 9216, divisible by 8
  int chunk = nb >> 3;
  bid = (bid & 7) * chunk + (bid >> 3);   // XCD slab swizzle (bijective)
  int slot = bid * 256 + threadIdx.x;
  int bin = slot / CAP;                   // const divisor -> magic mul
  int lane = slot - bin * CAP;            // waves bin-pure (CAP = 9*64)
  int c = cnt[bin];
  if (lane >= min(c, CAP)) return;
  float4 r = recs[slot];
  embed_point(make_float2(r.x, r.y), __float_as_int(r.z), tables, out);
}

__global__ __launch_bounds__(256) void ovf_kernel(
    const float2* __restrict__ xs, const int* __restrict__ ovf,
    const int* __restrict__ ovf_cnt, const float* __restrict__ tables,
    float* __restrict__ out) {
  int n = *ovf_cnt;
  for (int i = blockIdx.x * 256 + threadIdx.x; i < n; i += gridDim.x * 256) {
    int p = ovf[i];
    embed_point(xs[p], p, tables, out);
  }
}

// ---------------- fallback machinery (round-5, proven) ----------------------

__device__ __forceinline__ int bin_of(float2 xv) {
  int bx = min((int)(xv.x * 0.0625f), BINS_X - 1);
  int by = min((int)(xv.y * 0.0625f), BINS_X - 1);
  return bx * BINS_X + by;
}

__global__ __launch_bounds__(256) void hist_kernel(const float2* __restrict__ xs,
                                                   int* __restrict__ hist, int B) {
  int p = blockIdx.x * 256 + threadIdx.x;
  if (p >= B) return;
  atomicAdd(&hist[bin_of(xs[p])], 1);
}

__global__ __launch_bounds__(1024) void scan_kernel(const int* __restrict__ hist,
                                                    int* __restrict__ base) {
  __shared__ int part[1024];
  int tid = threadIdx.x;
  int loc[16];
  int s = 0;
#pragma unroll
  for (int j = 0; j < 16; ++j) { loc[j] = hist[tid * 16 + j]; s += loc[j]; }
  part[tid] = s;
  __syncthreads();
  for (int off = 1; off < 1024; off <<= 1) {
    int v = (tid >= off) ? part[tid - off] : 0;
    __syncthreads();
    part[tid] += v;
    __syncthreads();
  }
  int run = (tid == 0) ? 0 : part[tid - 1];
#pragma unroll
  for (int j = 0; j < 16; ++j) { base[tid * 16 + j] = run; run += loc[j]; }
}

__global__ __launch_bounds__(256) void scatter_packed(
    const float2* __restrict__ xs, int* __restrict__ base,
    float4* __restrict__ recs, int B) {
  int p = blockIdx.x * 256 + threadIdx.x;
  if (p >= B) return;
  float2 xv = xs[p];
  int pos = atomicAdd(&base[bin_of(xv)], 1);
  recs[pos] = make_float4(xv.x, xv.y, __int_as_float(p), 0.0f);
}

template <int MODE>  // 0 = unsorted, 2 = packed sorted
__global__ __launch_bounds__(256, 2) void hashenc_kernel(
    const float2* __restrict__ xs, const float4* __restrict__ recs,
    const float* __restrict__ tables, float* __restrict__ out, int B) {
  int bid = blockIdx.x;
  if (MODE != 0) {
    int nb = gridDim.x;
    int chunk = nb >> 3;
    bid = (bid & 7) * chunk + (bid >> 3);
  }
  int p = bid * 256 + threadIdx.x;
  if (p >= B) return;
  float2 xv;
  int orig;
  if (MODE == 2) {
    float4 r = recs[p];
    xv = make_float2(r.x, r.y);
    orig = __float_as_int(r.z);
  } else {
    xv = xs[p];
    orig = p;
  }
  embed_point(xv, orig, tables, out);
}

// ---------------- launch ----------------------------------------------------

extern "C" void kernel_launch(void* const* d_in, const int* in_sizes, int n_in,
                              void* d_out, int out_size, void* d_ws, size_t ws_size,
                              hipStream_t stream) {
  const float2* xs = (const float2*)d_in[0];
  const float* tables = (const float*)d_in[1];
  float* out = (float*)d_out;
  int B = in_sizes[0] / 2;
  int blocks = (B + 255) / 256;
  char* ws = (char*)d_ws;

  // capacity layout: recs (16B*SLOTS) | ovf (4B*B) | cnt (4B*NCB) | ovf_cnt(+pad)
  size_t c_recs = 0;
  size_t c_ovf = c_recs + (size_t)SLOTS * 16;
  size_t c_cnt = c_ovf + (size_t)B * 4;
  size_t c_ocnt = c_cnt + (size_t)NCB * 4;
  size_t need_cap = c_ocnt + 64;
  // round-5 packed layout: recs (16B*B) | hist | base
  size_t p_recs = 0, p_hist = p_recs + (size_t)B * 16, p_base = p_hist + (size_t)NBINS * 4;
  size_t need_packed = p_base + (size_t)NBINS * 4;

  bool grid_ok = (blocks & 7) == 0;
  if (grid_ok && ws_size >= need_cap && B == (1 << 21)) {
    float4* recs = (float4*)(ws + c_recs);
    int* ovf = (int*)(ws + c_ovf);
    int* cnt = (int*)(ws + c_cnt);
    int* ovf_cnt = (int*)(ws + c_ocnt);
    // zero cnt + ovf_cnt in one memset (contiguous)
    hipMemsetAsync(cnt, 0, (size_t)NCB * 4 + 64, stream);
    hipLaunchKernelGGL(scatter_cap, dim3(blocks), dim3(256), 0, stream,
                       xs, cnt, recs, ovf, ovf_cnt, B);
    hipLaunchKernelGGL(hashenc_cap, dim3(SLOTS / 256), dim3(256), 0, stream,
                       recs, cnt, tables, out);
    hipLaunchKernelGGL(ovf_kernel, dim3(32), dim3(256), 0, stream,
                       xs, ovf, ovf_cnt, tables, out);
  } else if (grid_ok && ws_size >= need_packed) {
    float4* recs = (float4*)(ws + p_recs);
    int* hist = (int*)(ws + p_hist);
    int* base = (int*)(ws + p_base);
    hipMemsetAsync(hist, 0, (size_t)NBINS * 4, stream);
    hipLaunchKernelGGL(hist_kernel, dim3(blocks), dim3(256), 0, stream, xs, hist, B);
    hipLaunchKernelGGL(scan_kernel, dim3(1), dim3(1024), 0, stream, hist, base);
    hipLaunchKernelGGL(scatter_packed, dim3(blocks), dim3(256), 0, stream, xs, base, recs, B);
    hipLaunchKernelGGL((hashenc_kernel<2>), dim3(blocks), dim3(256), 0, stream,
                       nullptr, recs, tables, out, B);
  } else {
    hipLaunchKernelGGL((hashenc_kernel<0>), dim3(blocks), dim3(256), 0, stream,
                       xs, nullptr, tables, out, B);
  }
}